// Round 7
// baseline (208.091 us; speedup 1.0000x reference)
//
#include <hip/hip_runtime.h>

// GRU trajectory decoder, fused single kernel. B=16384, D=256, HID=128, T=60, O=3.
// R7: max-occupancy restructure. 512-thr blocks (8 waves own hid 16w..16w+16),
// but only 16 batch rows per block (q=1) -> grid=1024 = 4 blocks/CU = 32
// waves/CU (HW max). Per-wave state ~80 persistent regs -> fits 128-reg cap
// (4 waves/SIMD) with NO spill (R2/R6 spilled at q>=2). All 8 waves read the
// same h rows from LDS (broadcast, conflict-free); 4 independent barrier
// domains per CU overlap each other's stalls. Gate math: R/Z weights+biases
// prescaled by -log2e (exp2 direct from MFMA), shared-rcp sigmoid pair,
// v_cvt_pk_bf16_f32 writeback. h double-buffered, 16B-chunk XOR swizzle.

typedef __attribute__((ext_vector_type(8))) short short8;
typedef __attribute__((ext_vector_type(4))) float f32x4;

#define MFMA16(a, b, c) __builtin_amdgcn_mfma_f32_16x16x32_bf16((a), (b), (c), 0, 0, 0)

__device__ __forceinline__ short f2bf(float x) {
    union { float f; unsigned u; } v; v.f = x;
    unsigned r = v.u + 0x7FFFu + ((v.u >> 16) & 1u);   // RNE
    return (short)(r >> 16);
}

__device__ __forceinline__ unsigned cvtpk(float lo, float hi) {
    unsigned d;
    asm("v_cvt_pk_bf16_f32 %0, %1, %2" : "=v"(d) : "v"(lo), "v"(hi));
    return d;
}

__device__ __forceinline__ short8 cvt8(const float* __restrict__ p) {
    f32x4 a = *(const f32x4*)p;
    f32x4 b = *(const f32x4*)(p + 4);
    short8 r;
    r[0] = f2bf(a[0]); r[1] = f2bf(a[1]); r[2] = f2bf(a[2]); r[3] = f2bf(a[3]);
    r[4] = f2bf(b[0]); r[5] = f2bf(b[1]); r[6] = f2bf(b[2]); r[7] = f2bf(b[3]);
    return r;
}
// scaled variant (fold -log2e into R/Z gate weights)
__device__ __forceinline__ short8 cvt8s(const float* __restrict__ p, float s) {
    f32x4 a = *(const f32x4*)p;
    f32x4 b = *(const f32x4*)(p + 4);
    short8 r;
    r[0] = f2bf(a[0] * s); r[1] = f2bf(a[1] * s); r[2] = f2bf(a[2] * s); r[3] = f2bf(a[3] * s);
    r[4] = f2bf(b[0] * s); r[5] = f2bf(b[1] * s); r[6] = f2bf(b[2] * s); r[7] = f2bf(b[3] * s);
    return r;
}

__global__ __launch_bounds__(512, 4) void gru_traj_kernel(
    const float* __restrict__ x,      // [B,256]
    const float* __restrict__ W_ih,   // [384,256]
    const float* __restrict__ W_hh,   // [384,128]
    const float* __restrict__ b_ih,   // [384]
    const float* __restrict__ b_hh,   // [384]
    const float* __restrict__ W_out,  // [3,128]
    const float* __restrict__ b_out,  // [3]
    float* __restrict__ out)          // [B,60,3]
{
    const int tid  = threadIdx.x;
    const int wid  = tid >> 6;          // wave 0..7 -> 16 hid dims
    const int lane = tid & 63;
    const int l15  = lane & 15;
    const int l4   = lane >> 4;         // 0..3
    const int b0   = blockIdx.x << 4;   // 16 batch rows per block
    const int hb   = wid << 4;          // wave's hid base

    const float SCL  = -1.442695041f;   // -log2(e)
    const float SCL2 = -2.885390082f;   // -2*log2(e)

    // h^T staging: [16 batch rows][128 hid] bf16, 16B-chunk XOR swizzle, dbuf
    __shared__ short hbuf[2][16 * 128];
    __shared__ short wobuf[3 * 136];    // W_out bf16, padded rows

    {   // h_0 = 0 (16*128 shorts = 1024 ints)
        int* z = (int*)hbuf[0];
        z[tid] = 0; z[tid + 512] = 0;
    }
    if (tid < 384) wobuf[(tid >> 7) * 136 + (tid & 127)] = f2bf(W_out[tid]);

    // ---- persistent W_hh A-frags: A[m=l15][k] = W_hh[g*128+hb+l15][k]
    short8 wfrag[3][4];
    #pragma unroll
    for (int kt = 0; kt < 4; ++kt) {
        wfrag[0][kt] = cvt8s(W_hh + (size_t)(      hb + l15) * 128 + kt * 32 + l4 * 8, SCL);
        wfrag[1][kt] = cvt8s(W_hh + (size_t)(128 + hb + l15) * 128 + kt * 32 + l4 * 8, SCL);
        wfrag[2][kt] = cvt8 (W_hh + (size_t)(256 + hb + l15) * 128 + kt * 32 + l4 * 8);
    }

    // biases over this lane's 4 hid dims (D rows l4*4+r)
    const int bbase = hb + l4 * 4;
    const f32x4 bNh = *(const f32x4*)(b_hh + 256 + bbase);
    const float bo0 = b_out[0], bo1 = b_out[1], bo2 = b_out[2];

    // ---- prologue: gi^T = W_ih * x^T (single batch chunk) ----
    f32x4 initR = (*(const f32x4*)(b_ih + bbase)       + *(const f32x4*)(b_hh + bbase))       * SCL;
    f32x4 initZ = (*(const f32x4*)(b_ih + 128 + bbase) + *(const f32x4*)(b_hh + 128 + bbase)) * SCL;
    f32x4 giN   = *(const f32x4*)(b_ih + 256 + bbase);
    #pragma unroll
    for (int kt = 0; kt < 8; ++kt) {
        short8 bx = cvt8(x + (size_t)(b0 + l15) * 256 + kt * 32 + l4 * 8);
        initR = MFMA16(cvt8s(W_ih + (size_t)(      hb + l15) * 256 + kt * 32 + l4 * 8, SCL), bx, initR);
        initZ = MFMA16(cvt8s(W_ih + (size_t)(128 + hb + l15) * 256 + kt * 32 + l4 * 8, SCL), bx, initZ);
        giN   = MFMA16(cvt8 (W_ih + (size_t)(256 + hb + l15) * 256 + kt * 32 + l4 * 8),      bx, giN);
    }

    float hq[4] = {0.f, 0.f, 0.f, 0.f};
    const int s8 = (wid << 2) | l4;   // lane's 8B slot (hid/4) in an h row

    __syncthreads();

    #pragma unroll 2
    for (int t = 0; t < 60; ++t) {
        const short* rb = hbuf[t & 1];
        short*       wb = hbuf[(t & 1) ^ 1];

        // B-frags: B[k][n=l15] = h[batch l15][hid k], swizzled chunks.
        // Identical across waves -> LDS broadcast.
        short8 af[4];
        #pragma unroll
        for (int kt = 0; kt < 4; ++kt)
            af[kt] = *(const short8*)(rb + l15 * 128 + (((kt * 4 + l4) ^ l15) & 15) * 8);

        // output head for h_t (out column t-1), rotated across waves
        if (t > 0 && wid == (t & 7)) {
            f32x4 oa = (f32x4){0.f, 0.f, 0.f, 0.f};
            #pragma unroll
            for (int kt = 0; kt < 4; ++kt) {
                short8 wo = {0, 0, 0, 0, 0, 0, 0, 0};
                if (l15 < 3) wo = *(const short8*)(wobuf + l15 * 136 + kt * 32 + l4 * 8);
                oa = MFMA16(wo, af[kt], oa);
            }
            if (l4 == 0) {
                float* op = out + (size_t)(b0 + l15) * 180 + (t - 1) * 3;
                op[0] = oa[0] + bo0; op[1] = oa[1] + bo1; op[2] = oa[2] + bo2;
            }
        }

        // gh^T = W_hh * h^T (+ prescaled gi/bias C-init)
        f32x4 aR = initR, aZ = initZ, aN = bNh;
        #pragma unroll
        for (int kt = 0; kt < 4; ++kt) {
            aR = MFMA16(wfrag[0][kt], af[kt], aR);
            aZ = MFMA16(wfrag[1][kt], af[kt], aZ);
            aN = MFMA16(wfrag[2][kt], af[kt], aN);
        }
        // gates; aR/aZ already = -log2e * preact -> exp2 direct
        float hn[4];
        #pragma unroll
        for (int r = 0; r < 4; ++r) {
            float eA = __builtin_amdgcn_exp2f(aR[r]);
            float eB = __builtin_amdgcn_exp2f(aZ[r]);
            float A  = 1.0f + eA, Bv = 1.0f + eB;
            float R  = __builtin_amdgcn_rcpf(A * Bv);     // shared rcp
            float rr = R * Bv;                            // sigmoid r
            float zz = R * A;                             // sigmoid z
            float sn = fmaf(rr, aN[r], giN[r]);
            float eC = __builtin_amdgcn_exp2f(sn * SCL2);
            float nn = fmaf(2.0f, __builtin_amdgcn_rcpf(1.0f + eC), -1.0f);  // tanh
            hn[r] = fmaf(zz, hq[r] - nn, nn);
            hq[r] = hn[r];
        }
        uint2 pk;
        pk.x = cvtpk(hn[0], hn[1]);
        pk.y = cvtpk(hn[2], hn[3]);
        *(uint2*)(wb + l15 * 128 + (((s8 >> 1) ^ l15) & 15) * 8 + (s8 & 1) * 4) = pk;

        __syncthreads();
    }

    // epilogue: out column 59 from h_60 (in hbuf[0])
    if (wid == 4) {
        const short* rb = hbuf[0];
        f32x4 oa = (f32x4){0.f, 0.f, 0.f, 0.f};
        #pragma unroll
        for (int kt = 0; kt < 4; ++kt) {
            short8 af = *(const short8*)(rb + l15 * 128 + (((kt * 4 + l4) ^ l15) & 15) * 8);
            short8 wo = {0, 0, 0, 0, 0, 0, 0, 0};
            if (l15 < 3) wo = *(const short8*)(wobuf + l15 * 136 + kt * 32 + l4 * 8);
            oa = MFMA16(wo, af, oa);
        }
        if (l4 == 0) {
            float* op = out + (size_t)(b0 + l15) * 180 + 59 * 3;
            op[0] = oa[0] + bo0; op[1] = oa[1] + bo1; op[2] = oa[2] + bo2;
        }
    }
}

extern "C" void kernel_launch(void* const* d_in, const int* in_sizes, int n_in,
                              void* d_out, int out_size, void* d_ws, size_t ws_size,
                              hipStream_t stream) {
    const float* x     = (const float*)d_in[0];
    const float* W_ih  = (const float*)d_in[1];
    const float* W_hh  = (const float*)d_in[2];
    const float* b_ih  = (const float*)d_in[3];
    const float* b_hh  = (const float*)d_in[4];
    const float* W_out = (const float*)d_in[5];
    const float* b_out = (const float*)d_in[6];
    float* out = (float*)d_out;

    const int B = in_sizes[0] / 256;   // 16384
    hipLaunchKernelGGL(gru_traj_kernel, dim3(B / 16), dim3(512), 0, stream,
                       x, W_ih, W_hh, b_ih, b_hh, W_out, b_out, out);
}

// Round 8
// 154.387 us; speedup vs baseline: 1.3479x; 1.3479x over previous
//
#include <hip/hip_runtime.h>

// GRU trajectory decoder, fused single kernel. B=16384, D=256, HID=128, T=60, O=3.
// R8 = R4 structure (best measured: 512 thr, 64 batch rows, q=4, wave owns 16
// hid dims, grid=256 = 1 block/CU, 2 waves/SIMD, no spill) + issue-work cuts:
//  - R/Z gate weights+biases prescaled by -log2e -> exp2 directly on MFMA out
//  - shared-rcp sigmoid pair (5 trans/elem, was 6)
//  - v_cvt_pk_bf16_f32 h-writeback
//  - all LDS addresses hoisted to loop-invariant byte offsets (ds base+imm)
//  - af double-buffered across q chunks (post-barrier LDS latency hidden)
// Occupancy pushes (R2/R6/R7) all spilled: working set ~160-190 regs is real;
// stay at 2 waves/SIMD with 256-reg budget.

typedef __attribute__((ext_vector_type(8))) short short8;
typedef __attribute__((ext_vector_type(4))) float f32x4;

#define MFMA16(a, b, c) __builtin_amdgcn_mfma_f32_16x16x32_bf16((a), (b), (c), 0, 0, 0)

__device__ __forceinline__ short f2bf(float x) {
    union { float f; unsigned u; } v; v.f = x;
    unsigned r = v.u + 0x7FFFu + ((v.u >> 16) & 1u);   // RNE
    return (short)(r >> 16);
}

__device__ __forceinline__ unsigned cvtpk(float lo, float hi) {
    unsigned d;
    asm("v_cvt_pk_bf16_f32 %0, %1, %2" : "=v"(d) : "v"(lo), "v"(hi));
    return d;
}

__device__ __forceinline__ short8 cvt8(const float* __restrict__ p) {
    f32x4 a = *(const f32x4*)p;
    f32x4 b = *(const f32x4*)(p + 4);
    short8 r;
    r[0] = f2bf(a[0]); r[1] = f2bf(a[1]); r[2] = f2bf(a[2]); r[3] = f2bf(a[3]);
    r[4] = f2bf(b[0]); r[5] = f2bf(b[1]); r[6] = f2bf(b[2]); r[7] = f2bf(b[3]);
    return r;
}
// scaled variant (fold -log2e into R/Z gate weights)
__device__ __forceinline__ short8 cvt8s(const float* __restrict__ p, float s) {
    f32x4 a = *(const f32x4*)p;
    f32x4 b = *(const f32x4*)(p + 4);
    short8 r;
    r[0] = f2bf(a[0] * s); r[1] = f2bf(a[1] * s); r[2] = f2bf(a[2] * s); r[3] = f2bf(a[3] * s);
    r[4] = f2bf(b[0] * s); r[5] = f2bf(b[1] * s); r[6] = f2bf(b[2] * s); r[7] = f2bf(b[3] * s);
    return r;
}

__global__ __launch_bounds__(512, 2) void gru_traj_kernel(
    const float* __restrict__ x,      // [B,256]
    const float* __restrict__ W_ih,   // [384,256]
    const float* __restrict__ W_hh,   // [384,128]
    const float* __restrict__ b_ih,   // [384]
    const float* __restrict__ b_hh,   // [384]
    const float* __restrict__ W_out,  // [3,128]
    const float* __restrict__ b_out,  // [3]
    float* __restrict__ out)          // [B,60,3]
{
    const int tid  = threadIdx.x;
    const int wid  = tid >> 6;          // wave 0..7 -> hid chunk [16w,16w+16)
    const int lane = tid & 63;
    const int l15  = lane & 15;
    const int l4   = lane >> 4;         // 0..3
    const int b0   = blockIdx.x << 6;   // 64 batch rows per block
    const int hb   = wid << 4;

    const float SCL  = -1.442695041f;   // -log2(e)
    const float SCL2 = -2.885390082f;   // -2*log2(e)

    // h^T staging: [64 batch rows][128 hid] bf16, 16B-chunk XOR swizzle, dbuf
    __shared__ short hbuf[2][64 * 128];
    __shared__ short wobuf[3 * 136];    // W_out bf16, padded rows

    {   // h_0 = 0
        int* z = (int*)hbuf[0];
        #pragma unroll
        for (int i = 0; i < 8; ++i) z[tid + i * 512] = 0;
    }
    if (tid < 384) wobuf[(tid >> 7) * 136 + (tid & 127)] = f2bf(W_out[tid]);

    // ---- persistent W_hh A-frags: A[m=l15][k] = W_hh[g*128+hb+l15][k]
    short8 wfrag[3][4];
    #pragma unroll
    for (int kt = 0; kt < 4; ++kt) {
        wfrag[0][kt] = cvt8s(W_hh + (size_t)(      hb + l15) * 128 + kt * 32 + l4 * 8, SCL);
        wfrag[1][kt] = cvt8s(W_hh + (size_t)(128 + hb + l15) * 128 + kt * 32 + l4 * 8, SCL);
        wfrag[2][kt] = cvt8 (W_hh + (size_t)(256 + hb + l15) * 128 + kt * 32 + l4 * 8);
    }

    // biases over this lane's 4 hid dims (D rows l4*4+r); R/Z prescaled
    const int bbase = hb + l4 * 4;
    const f32x4 bR4 = (*(const f32x4*)(b_ih + bbase)       + *(const f32x4*)(b_hh + bbase))       * SCL;
    const f32x4 bZ4 = (*(const f32x4*)(b_ih + 128 + bbase) + *(const f32x4*)(b_hh + 128 + bbase)) * SCL;
    const f32x4 bNi = *(const f32x4*)(b_ih + 256 + bbase);
    const f32x4 bNh = *(const f32x4*)(b_hh + 256 + bbase);
    const float bo0 = b_out[0], bo1 = b_out[1], bo2 = b_out[2];

    // ---- prologue: gi^T = W_ih * x^T per batch-chunk q (R/Z prescaled) ----
    f32x4 initR[4], initZ[4], giN[4];
    #pragma unroll
    for (int q = 0; q < 4; ++q) { initR[q] = bR4; initZ[q] = bZ4; giN[q] = bNi; }
    #pragma unroll
    for (int kt = 0; kt < 8; ++kt) {
        short8 a0 = cvt8s(W_ih + (size_t)(      hb + l15) * 256 + kt * 32 + l4 * 8, SCL);
        short8 a1 = cvt8s(W_ih + (size_t)(128 + hb + l15) * 256 + kt * 32 + l4 * 8, SCL);
        short8 a2 = cvt8 (W_ih + (size_t)(256 + hb + l15) * 256 + kt * 32 + l4 * 8);
        #pragma unroll
        for (int q = 0; q < 4; ++q) {
            short8 bx = cvt8(x + (size_t)(b0 + q * 16 + l15) * 256 + kt * 32 + l4 * 8);
            initR[q] = MFMA16(a0, bx, initR[q]);
            initZ[q] = MFMA16(a1, bx, initZ[q]);
            giN [q] = MFMA16(a2, bx, giN [q]);
        }
    }

    float hq[4][4];
    #pragma unroll
    for (int q = 0; q < 4; ++q)
        #pragma unroll
        for (int r = 0; r < 4; ++r) hq[q][r] = 0.f;

    // loop-invariant LDS byte offsets (swizzled); in-loop addrs are base+imm
    const int s8 = (wid << 2) | l4;     // lane's 8B slot (hid/4) in an h row
    int roff[4];
    #pragma unroll
    for (int kt = 0; kt < 4; ++kt)
        roff[kt] = (l15 * 128 + (((kt * 4 + l4) ^ l15) & 15) * 8) * 2;
    const int woff = (l15 * 128 + (((s8 >> 1) ^ l15) & 15) * 8 + (s8 & 1) * 4) * 2;

    __syncthreads();

    #pragma unroll 2
    for (int t = 0; t < 60; ++t) {
        const char* rb = (const char*)hbuf[t & 1];
        char*       wb = (char*)hbuf[(t & 1) ^ 1];

        // af double-buffer across q: post-barrier LDS latency hides under
        // previous q's MFMA + gate math.
        short8 afc[4], afn[4];
        #pragma unroll
        for (int kt = 0; kt < 4; ++kt)
            afc[kt] = *(const short8*)(rb + roff[kt]);

        #pragma unroll
        for (int q = 0; q < 4; ++q) {
            if (q < 3) {
                #pragma unroll
                for (int kt = 0; kt < 4; ++kt)
                    afn[kt] = *(const short8*)(rb + roff[kt] + (q + 1) * 4096);
            }

            // gh^T = W_hh * h^T (+ prescaled gi/bias C-init)
            f32x4 aR = initR[q], aZ = initZ[q], aN = bNh;
            #pragma unroll
            for (int kt = 0; kt < 4; ++kt) {
                aR = MFMA16(wfrag[0][kt], afc[kt], aR);
                aZ = MFMA16(wfrag[1][kt], afc[kt], aZ);
                aN = MFMA16(wfrag[2][kt], afc[kt], aN);
            }

            // output head for h_t (out column t-1), rotated across waves
            if (t > 0 && wid == ((q + t) & 7)) {
                f32x4 oa = (f32x4){0.f, 0.f, 0.f, 0.f};
                #pragma unroll
                for (int kt = 0; kt < 4; ++kt) {
                    short8 wo = {0, 0, 0, 0, 0, 0, 0, 0};
                    if (l15 < 3) wo = *(const short8*)(wobuf + l15 * 136 + kt * 32 + l4 * 8);
                    oa = MFMA16(wo, afc[kt], oa);
                }
                if (l4 == 0) {
                    float* op = out + (size_t)(b0 + q * 16 + l15) * 180 + (t - 1) * 3;
                    op[0] = oa[0] + bo0; op[1] = oa[1] + bo1; op[2] = oa[2] + bo2;
                }
            }

            // gates; aR/aZ already = -log2e * preact -> exp2 direct
            float hn[4];
            #pragma unroll
            for (int r = 0; r < 4; ++r) {
                float eA = __builtin_amdgcn_exp2f(aR[r]);
                float eB = __builtin_amdgcn_exp2f(aZ[r]);
                float A  = 1.0f + eA, Bv = 1.0f + eB;
                float R  = __builtin_amdgcn_rcpf(A * Bv);     // shared rcp
                float rr = R * Bv;                            // sigmoid r
                float zz = R * A;                             // sigmoid z
                float sn = fmaf(rr, aN[r], giN[q][r]);
                float eC = __builtin_amdgcn_exp2f(sn * SCL2);
                float nn = fmaf(2.0f, __builtin_amdgcn_rcpf(1.0f + eC), -1.0f);  // tanh
                hn[r] = fmaf(zz, hq[q][r] - nn, nn);
                hq[q][r] = hn[r];
            }
            uint2 pk;
            pk.x = cvtpk(hn[0], hn[1]);
            pk.y = cvtpk(hn[2], hn[3]);
            *(uint2*)(wb + woff + q * 4096) = pk;

            #pragma unroll
            for (int kt = 0; kt < 4; ++kt) afc[kt] = afn[kt];
        }
        __syncthreads();
    }

    // epilogue: out column 59 from h_60 (in hbuf[0])
    if (wid < 4) {
        const int q = wid;
        const char* rb = (const char*)hbuf[0];
        f32x4 oa = (f32x4){0.f, 0.f, 0.f, 0.f};
        #pragma unroll
        for (int kt = 0; kt < 4; ++kt) {
            short8 af = *(const short8*)(rb + roff[kt] + q * 4096);
            short8 wo = {0, 0, 0, 0, 0, 0, 0, 0};
            if (l15 < 3) wo = *(const short8*)(wobuf + l15 * 136 + kt * 32 + l4 * 8);
            oa = MFMA16(wo, af, oa);
        }
        if (l4 == 0) {
            float* op = out + (size_t)(b0 + q * 16 + l15) * 180 + 59 * 3;
            op[0] = oa[0] + bo0; op[1] = oa[1] + bo1; op[2] = oa[2] + bo2;
        }
    }
}

extern "C" void kernel_launch(void* const* d_in, const int* in_sizes, int n_in,
                              void* d_out, int out_size, void* d_ws, size_t ws_size,
                              hipStream_t stream) {
    const float* x     = (const float*)d_in[0];
    const float* W_ih  = (const float*)d_in[1];
    const float* W_hh  = (const float*)d_in[2];
    const float* b_ih  = (const float*)d_in[3];
    const float* b_hh  = (const float*)d_in[4];
    const float* W_out = (const float*)d_in[5];
    const float* b_out = (const float*)d_in[6];
    float* out = (float*)d_out;

    const int B = in_sizes[0] / 256;   // 16384
    hipLaunchKernelGGL(gru_traj_kernel, dim3(B / 64), dim3(512), 0, stream,
                       x, W_ih, W_hh, b_ih, b_hh, W_out, b_out, out);
}

// Round 9
// 149.709 us; speedup vs baseline: 1.3900x; 1.0313x over previous
//
#include <hip/hip_runtime.h>

// GRU trajectory decoder, fused single kernel. B=16384, D=256, HID=128, T=60, O=3.
// R9 = R8 structure (512 thr, 64 batch rows, q=4, wave owns 16 hid dims,
// grid=256 = 1 block/CU, 2 waves/SIMD, zero spill) + VALU issue cuts:
//  - af alternating named buffers (no 64-mov copy/step), distance-2 prefetch
//  - gate math vectorized on f32x4 -> packed dual-f32 VALU (v_pk_*_f32)
//  - W_out fragments in registers (head: no LDS reads; regs have headroom)
//  - R/Z weights+biases prescaled by -log2e; shared-rcp sigmoid pair;
//    v_cvt_pk_bf16_f32 writeback; swizzled loop-invariant LDS offsets.
// Occupancy is grid/structure-limited (1 block/CU); forcing 4 waves/SIMD pins
// arch VGPRs at 64 and spills (R2/R6/R7) -- stay at 2 waves/SIMD.

typedef __attribute__((ext_vector_type(8))) short short8;
typedef __attribute__((ext_vector_type(4))) float f32x4;

#define MFMA16(a, b, c) __builtin_amdgcn_mfma_f32_16x16x32_bf16((a), (b), (c), 0, 0, 0)

__device__ __forceinline__ short f2bf(float x) {
    union { float f; unsigned u; } v; v.f = x;
    unsigned r = v.u + 0x7FFFu + ((v.u >> 16) & 1u);   // RNE
    return (short)(r >> 16);
}

__device__ __forceinline__ unsigned cvtpk(float lo, float hi) {
    unsigned d;
    asm("v_cvt_pk_bf16_f32 %0, %1, %2" : "=v"(d) : "v"(lo), "v"(hi));
    return d;
}

__device__ __forceinline__ short8 cvt8(const float* __restrict__ p) {
    f32x4 a = *(const f32x4*)p;
    f32x4 b = *(const f32x4*)(p + 4);
    short8 r;
    r[0] = f2bf(a[0]); r[1] = f2bf(a[1]); r[2] = f2bf(a[2]); r[3] = f2bf(a[3]);
    r[4] = f2bf(b[0]); r[5] = f2bf(b[1]); r[6] = f2bf(b[2]); r[7] = f2bf(b[3]);
    return r;
}
// scaled variant (fold -log2e into R/Z gate weights)
__device__ __forceinline__ short8 cvt8s(const float* __restrict__ p, float s) {
    f32x4 a = *(const f32x4*)p;
    f32x4 b = *(const f32x4*)(p + 4);
    short8 r;
    r[0] = f2bf(a[0] * s); r[1] = f2bf(a[1] * s); r[2] = f2bf(a[2] * s); r[3] = f2bf(a[3] * s);
    r[4] = f2bf(b[0] * s); r[5] = f2bf(b[1] * s); r[6] = f2bf(b[2] * s); r[7] = f2bf(b[3] * s);
    return r;
}

__global__ __launch_bounds__(512, 2) void gru_traj_kernel(
    const float* __restrict__ x,      // [B,256]
    const float* __restrict__ W_ih,   // [384,256]
    const float* __restrict__ W_hh,   // [384,128]
    const float* __restrict__ b_ih,   // [384]
    const float* __restrict__ b_hh,   // [384]
    const float* __restrict__ W_out,  // [3,128]
    const float* __restrict__ b_out,  // [3]
    float* __restrict__ out)          // [B,60,3]
{
    const int tid  = threadIdx.x;
    const int wid  = tid >> 6;          // wave 0..7 -> hid chunk [16w,16w+16)
    const int lane = tid & 63;
    const int l15  = lane & 15;
    const int l4   = lane >> 4;         // 0..3
    const int b0   = blockIdx.x << 6;   // 64 batch rows per block
    const int hb   = wid << 4;

    const float SCL  = -1.442695041f;   // -log2(e)
    const float SCL2 = -2.885390082f;   // -2*log2(e)

    // h^T staging: [64 batch rows][128 hid] bf16, 16B-chunk XOR swizzle, dbuf
    __shared__ short hbuf[2][64 * 128];

    {   // h_0 = 0
        int* z = (int*)hbuf[0];
        #pragma unroll
        for (int i = 0; i < 8; ++i) z[tid + i * 512] = 0;
    }

    // ---- persistent W_hh A-frags: A[m=l15][k] = W_hh[g*128+hb+l15][k]
    short8 wfrag[3][4];
    #pragma unroll
    for (int kt = 0; kt < 4; ++kt) {
        wfrag[0][kt] = cvt8s(W_hh + (size_t)(      hb + l15) * 128 + kt * 32 + l4 * 8, SCL);
        wfrag[1][kt] = cvt8s(W_hh + (size_t)(128 + hb + l15) * 128 + kt * 32 + l4 * 8, SCL);
        wfrag[2][kt] = cvt8 (W_hh + (size_t)(256 + hb + l15) * 128 + kt * 32 + l4 * 8);
    }
    // W_out fragments in registers (rows n>=3 zero)
    short8 wofrag[4];
    #pragma unroll
    for (int kt = 0; kt < 4; ++kt) {
        short8 f = {0, 0, 0, 0, 0, 0, 0, 0};
        if (l15 < 3) f = cvt8(W_out + l15 * 128 + kt * 32 + l4 * 8);
        wofrag[kt] = f;
    }

    // biases over this lane's 4 hid dims (D rows l4*4+r); R/Z prescaled
    const int bbase = hb + l4 * 4;
    const f32x4 bR4 = (*(const f32x4*)(b_ih + bbase)       + *(const f32x4*)(b_hh + bbase))       * SCL;
    const f32x4 bZ4 = (*(const f32x4*)(b_ih + 128 + bbase) + *(const f32x4*)(b_hh + 128 + bbase)) * SCL;
    const f32x4 bNi = *(const f32x4*)(b_ih + 256 + bbase);
    const f32x4 bNh = *(const f32x4*)(b_hh + 256 + bbase);
    const float bo0 = b_out[0], bo1 = b_out[1], bo2 = b_out[2];

    // ---- prologue: gi^T = W_ih * x^T per batch-chunk q (R/Z prescaled) ----
    f32x4 initR[4], initZ[4], giN[4];
    #pragma unroll
    for (int q = 0; q < 4; ++q) { initR[q] = bR4; initZ[q] = bZ4; giN[q] = bNi; }
    #pragma unroll
    for (int kt = 0; kt < 8; ++kt) {
        short8 a0 = cvt8s(W_ih + (size_t)(      hb + l15) * 256 + kt * 32 + l4 * 8, SCL);
        short8 a1 = cvt8s(W_ih + (size_t)(128 + hb + l15) * 256 + kt * 32 + l4 * 8, SCL);
        short8 a2 = cvt8 (W_ih + (size_t)(256 + hb + l15) * 256 + kt * 32 + l4 * 8);
        #pragma unroll
        for (int q = 0; q < 4; ++q) {
            short8 bx = cvt8(x + (size_t)(b0 + q * 16 + l15) * 256 + kt * 32 + l4 * 8);
            initR[q] = MFMA16(a0, bx, initR[q]);
            initZ[q] = MFMA16(a1, bx, initZ[q]);
            giN [q] = MFMA16(a2, bx, giN [q]);
        }
    }

    f32x4 hq[4];
    #pragma unroll
    for (int q = 0; q < 4; ++q) hq[q] = (f32x4){0.f, 0.f, 0.f, 0.f};

    // loop-invariant LDS byte offsets (swizzled); in-loop addrs are base+imm
    const int s8 = (wid << 2) | l4;     // lane's 8B slot (hid/4) in an h row
    int roff[4];
    #pragma unroll
    for (int kt = 0; kt < 4; ++kt)
        roff[kt] = (l15 * 128 + (((kt * 4 + l4) ^ l15) & 15) * 8) * 2;
    const int woff = (l15 * 128 + (((s8 >> 1) ^ l15) & 15) * 8 + (s8 & 1) * 4) * 2;

    __syncthreads();

#define LOADQ(buf, q)                                             \
    {                                                             \
        _Pragma("unroll")                                         \
        for (int kt = 0; kt < 4; ++kt)                            \
            buf[kt] = *(const short8*)(rb + roff[kt] + (q) * 4096); \
    }

#define PROCQ(q, AF)                                                          \
    {                                                                         \
        f32x4 aR = initR[q], aZ = initZ[q], aN = bNh;                         \
        _Pragma("unroll")                                                     \
        for (int kt = 0; kt < 4; ++kt) {                                      \
            aR = MFMA16(wfrag[0][kt], AF[kt], aR);                            \
            aZ = MFMA16(wfrag[1][kt], AF[kt], aZ);                            \
            aN = MFMA16(wfrag[2][kt], AF[kt], aN);                            \
        }                                                                     \
        if (t > 0 && wid == (((q) + t) & 7)) {                                \
            f32x4 oa = (f32x4){0.f, 0.f, 0.f, 0.f};                           \
            _Pragma("unroll")                                                 \
            for (int kt = 0; kt < 4; ++kt) oa = MFMA16(wofrag[kt], AF[kt], oa); \
            if (l4 == 0) {                                                    \
                float* op = out + (size_t)(b0 + (q) * 16 + l15) * 180 + (t - 1) * 3; \
                op[0] = oa[0] + bo0; op[1] = oa[1] + bo1; op[2] = oa[2] + bo2; \
            }                                                                 \
        }                                                                     \
        f32x4 eA, eB;                                                         \
        _Pragma("unroll")                                                     \
        for (int r = 0; r < 4; ++r) {                                         \
            eA[r] = __builtin_amdgcn_exp2f(aR[r]);                            \
            eB[r] = __builtin_amdgcn_exp2f(aZ[r]);                            \
        }                                                                     \
        f32x4 A  = eA + 1.0f;                                                 \
        f32x4 Bv = eB + 1.0f;                                                 \
        f32x4 P  = A * Bv;                                                    \
        f32x4 R;                                                              \
        _Pragma("unroll")                                                     \
        for (int r = 0; r < 4; ++r) R[r] = __builtin_amdgcn_rcpf(P[r]);       \
        f32x4 rr = R * Bv;                                                    \
        f32x4 zz = R * A;                                                     \
        f32x4 sn = rr * aN + giN[q];                                          \
        f32x4 eC;                                                             \
        _Pragma("unroll")                                                     \
        for (int r = 0; r < 4; ++r) eC[r] = __builtin_amdgcn_exp2f(sn[r] * SCL2); \
        f32x4 C1 = eC + 1.0f;                                                 \
        f32x4 T;                                                              \
        _Pragma("unroll")                                                     \
        for (int r = 0; r < 4; ++r) T[r] = __builtin_amdgcn_rcpf(C1[r]);      \
        f32x4 nn = 2.0f * T - 1.0f;                                           \
        f32x4 hn = (hq[q] - nn) * zz + nn;                                    \
        hq[q] = hn;                                                           \
        uint2 pk;                                                             \
        pk.x = cvtpk(hn[0], hn[1]);                                           \
        pk.y = cvtpk(hn[2], hn[3]);                                           \
        *(uint2*)(wb + woff + (q) * 4096) = pk;                               \
    }

    #pragma unroll 2
    for (int t = 0; t < 60; ++t) {
        const char* rb = (const char*)hbuf[t & 1];
        char*       wb = (char*)hbuf[(t & 1) ^ 1];

        short8 afA[4], afB[4];
        LOADQ(afA, 0);
        LOADQ(afB, 1);
        PROCQ(0, afA);
        LOADQ(afA, 2);
        PROCQ(1, afB);
        LOADQ(afB, 3);
        PROCQ(2, afA);
        PROCQ(3, afB);

        __syncthreads();
    }

    // epilogue: out column 59 from h_60 (in hbuf[0])
    if (wid < 4) {
        const int q = wid;
        const char* rb = (const char*)hbuf[0];
        f32x4 oa = (f32x4){0.f, 0.f, 0.f, 0.f};
        #pragma unroll
        for (int kt = 0; kt < 4; ++kt) {
            short8 af = *(const short8*)(rb + roff[kt] + q * 4096);
            oa = MFMA16(wofrag[kt], af, oa);
        }
        if (l4 == 0) {
            float* op = out + (size_t)(b0 + q * 16 + l15) * 180 + 59 * 3;
            op[0] = oa[0] + bo0; op[1] = oa[1] + bo1; op[2] = oa[2] + bo2;
        }
    }
#undef LOADQ
#undef PROCQ
}

extern "C" void kernel_launch(void* const* d_in, const int* in_sizes, int n_in,
                              void* d_out, int out_size, void* d_ws, size_t ws_size,
                              hipStream_t stream) {
    const float* x     = (const float*)d_in[0];
    const float* W_ih  = (const float*)d_in[1];
    const float* W_hh  = (const float*)d_in[2];
    const float* b_ih  = (const float*)d_in[3];
    const float* b_hh  = (const float*)d_in[4];
    const float* W_out = (const float*)d_in[5];
    const float* b_out = (const float*)d_in[6];
    float* out = (float*)d_out;

    const int B = in_sizes[0] / 256;   // 16384
    hipLaunchKernelGGL(gru_traj_kernel, dim3(B / 64), dim3(512), 0, stream,
                       x, W_ih, W_hh, b_ih, b_hh, W_out, b_out, out);
}